// Round 2
// baseline (422.272 us; speedup 1.0000x reference)
//
#include <hip/hip_runtime.h>
#include <hip/hip_bf16.h>
#include <math.h>

#define BATCH   2
#define N_NODES 10000
#define E_EDGES 160000
#define BN      (BATCH * N_NODES)       // 20000
#define BE      (BATCH * E_EDGES)       // 320000
#define ND      128
#define ED      64
#define HID     256
#define K1      320   // 2*ND + ED
#define K2      256
#define K1U     384   // ND + HID
#define NOUT    128
#define TM      64    // node-kernel rows per block
#define TME     64    // edge-kernel rows per block
#define LDH     264   // H stride (bf16), 256+8
#define SCAN_BLOCKS ((BN + 1023) / 1024)   // 20

typedef __attribute__((ext_vector_type(8))) short bf16x8;
typedef __attribute__((ext_vector_type(4))) float f32x4;

// ---------- static device buffers (no ws/d_out aliasing games) ----------
__device__ float          g_P[(size_t)BN * 512];        // [n][0:256)=src-part, [256:512)=dst-part (fp32)
__device__ unsigned short g_nodef_bf[(size_t)BN * ND];  // bf16 node features
__device__ unsigned short g_w1ut[K1U * HID];            // node L1 weights, n-major bf16
__device__ unsigned short g_w2ut[K2 * NOUT];            // node L2 weights, n-major bf16

// fast tanh-gelu: tanh(u) = 1 - 2/(exp(2u)+1); both tails saturate correctly.
__device__ __forceinline__ float gelu_tanh(float x) {
    float u = 0.7978845608028654f * (x + 0.044715f * x * x * x);
    float e = __expf(2.0f * u);
    float t = 1.0f - 2.0f * __builtin_amdgcn_rcpf(e + 1.0f);
    return 0.5f * x * (1.0f + t);
}

__device__ __forceinline__ unsigned short f2bf(float f) {
    __hip_bfloat16 h = __float2bfloat16(f);
    return *reinterpret_cast<unsigned short*>(&h);
}

__device__ __forceinline__ float bf2f(unsigned short u) {
    unsigned int x = ((unsigned int)u) << 16;
    return *reinterpret_cast<float*>(&x);
}

// ---------- prep kernels ----------

__global__ __launch_bounds__(256) void f32_to_bf16_vec(
    const float* __restrict__ in, int n4)
{
    int i = blockIdx.x * blockDim.x + threadIdx.x;
    if (i < n4) {
        float4 v = ((const float4*)in)[i];
        ushort4 o;
        o.x = f2bf(v.x); o.y = f2bf(v.y); o.z = f2bf(v.z); o.w = f2bf(v.w);
        ((ushort4*)g_nodef_bf)[i] = o;
    }
}

__global__ __launch_bounds__(256) void w_transpose_bf16(
    const float* __restrict__ w, unsigned short* __restrict__ wt, int K, int N)
{
    int id = blockIdx.x * blockDim.x + threadIdx.x;
    if (id < K * N) {
        int k = id % K;
        int n = id / K;
        wt[id] = f2bf(w[k * N + n]);
    }
}

__global__ __launch_bounds__(256) void prep_upd_weights(
    const float* __restrict__ W1u, const float* __restrict__ W2u)
{
    int id = blockIdx.x * blockDim.x + threadIdx.x;
    if (id < K1U * HID) {                      // g_w1ut[n][k] = W1u[k][n]
        int k = id % K1U, n = id / K1U;
        g_w1ut[id] = f2bf(W1u[(size_t)k * HID + n]);
    }
    if (id < K2 * NOUT) {                      // g_w2ut[n][k] = W2u[k][n]
        int k = id % K2, n = id / K2;
        g_w2ut[id] = f2bf(W2u[(size_t)k * NOUT + n]);
    }
}

__global__ __launch_bounds__(256) void dst_hist(
    const int* __restrict__ eidx, int* __restrict__ hist)
{
    int e = blockIdx.x * blockDim.x + threadIdx.x;
    if (e < BE) {
        int dst = eidx[2 * e + 1];
        int b   = e / E_EDGES;
        atomicAdd(&hist[b * N_NODES + dst], 1);
    }
}

// ---------- hierarchical scan ----------

__global__ __launch_bounds__(1024) void scan_partial(
    const int* __restrict__ hist, int* __restrict__ offs, int* __restrict__ bsum)
{
    __shared__ int buf[1024];
    int tid = threadIdx.x;
    int i   = blockIdx.x * 1024 + tid;
    int v   = (i < BN) ? hist[i] : 0;
    buf[tid] = v;
    __syncthreads();
    #pragma unroll
    for (int d = 1; d < 1024; d <<= 1) {
        int t = (tid >= d) ? buf[tid - d] : 0;
        __syncthreads();
        buf[tid] += t;
        __syncthreads();
    }
    int incl = buf[tid];
    if (i < BN) offs[i] = incl - v;
    if (tid == 1023) bsum[blockIdx.x] = incl;
}

__global__ __launch_bounds__(64) void scan_sums(int* __restrict__ bsum)
{
    if (threadIdx.x == 0) {
        int acc = 0;
        for (int b = 0; b < SCAN_BLOCKS; ++b) {
            int t = bsum[b];
            bsum[b] = acc;
            acc += t;
        }
    }
}

__global__ __launch_bounds__(1024) void scan_add(
    int* __restrict__ offs, const int* __restrict__ bsum)
{
    int i = blockIdx.x * 1024 + threadIdx.x;
    if (i < BN) offs[i] += bsum[blockIdx.x];
}

__global__ __launch_bounds__(256) void dst_scatter(
    const int* __restrict__ eidx, int* __restrict__ offs, int* __restrict__ perm)
{
    int e = blockIdx.x * blockDim.x + threadIdx.x;
    if (e < BE) {
        int dst  = eidx[2 * e + 1];
        int b    = e / E_EDGES;
        int pos  = atomicAdd(&offs[b * N_NODES + dst], 1);
        perm[pos] = e;
    }
}

// ---------- P GEMM: g_P[n][0:512) = nodef_bf @ [W1m[0:128] | W1m[128:256]] ----------
// 512 thr / 8 waves; wave w covers output cols w*64..w*64+63.
// waves 0-3: src-part (W1m k-rows 0..127); waves 4-7: dst-part (k-rows 128..255).
// A direct from global (contiguous rows), B (w1t, n-major) direct from global. No LDS.
__global__ __launch_bounds__(512, 2) void pgemm(const unsigned short* __restrict__ w1t)
{
    const int tid  = threadIdx.x;
    const int wave = tid >> 6;
    const int lane = tid & 63;
    const int quad = lane >> 4;
    const int r16  = lane & 15;
    const int n0   = blockIdx.x * TM;

    const int jb   = (wave & 3) * 64;              // col base within 256
    const int koff = (wave < 4) ? 0 : 128;         // W1m k-row offset
    const int cb   = (wave < 4) ? 0 : 256;         // output col-base add

    f32x4 acc[4][4];
    #pragma unroll
    for (int mt = 0; mt < 4; ++mt)
        #pragma unroll
        for (int nt = 0; nt < 4; ++nt)
            acc[mt][nt] = (f32x4){0.f, 0.f, 0.f, 0.f};

    for (int ks = 0; ks < ND / 32; ++ks) {
        bf16x8 af[4], bfg[4];
        #pragma unroll
        for (int mt = 0; mt < 4; ++mt) {
            int row = n0 + mt * 16 + r16; if (row >= BN) row = BN - 1;
            af[mt] = *(const bf16x8*)&g_nodef_bf[(size_t)row * ND + ks * 32 + quad * 8];
        }
        #pragma unroll
        for (int nt = 0; nt < 4; ++nt)
            bfg[nt] = *(const bf16x8*)&w1t[(size_t)(jb + nt * 16 + r16) * K1
                                           + koff + ks * 32 + quad * 8];
        #pragma unroll
        for (int mt = 0; mt < 4; ++mt)
            #pragma unroll
            for (int nt = 0; nt < 4; ++nt)
                acc[mt][nt] = __builtin_amdgcn_mfma_f32_16x16x32_bf16(
                    af[mt], bfg[nt], acc[mt][nt], 0, 0, 0);
    }

    #pragma unroll
    for (int nt = 0; nt < 4; ++nt) {
        int j = cb + jb + nt * 16 + r16;
        #pragma unroll
        for (int mt = 0; mt < 4; ++mt)
            #pragma unroll
            for (int r = 0; r < 4; ++r) {
                int row = n0 + mt * 16 + quad * 4 + r;
                if (row < BN) g_P[(size_t)row * 512 + j] = acc[mt][nt][r];
            }
    }
}

// ---------- edge MLP ----------
// Per block (64 edges): stage edge features -> sE; GEMM1 (K=64, ef @ W1e);
// epilogue gathers P[src]+P[dst]+bias, gelu -> sH; GEMM2 (K=256) -> run-reduce atomics.
// LDS 41,984 B (+768 idx): sE 8 KiB, sH 33,792 B. No node-feature gather at all.
#define EK_SE   0
#define EK_SH   8192
#define EK_SMEM (8192 + TME * LDH * 2)   // 41,984

__global__ __launch_bounds__(512, 4) void edge_mlp_mfma(
    const int*            __restrict__ eidx,
    const float*          __restrict__ edgef,
    const int*            __restrict__ perm,
    const unsigned short* __restrict__ w1t,       // [256][320] bf16 n-major
    const float*          __restrict__ b1m,
    const unsigned short* __restrict__ w2t,       // [256][256] bf16 n-major
    const float*          __restrict__ b2m,
    float* __restrict__ agg)
{
    __shared__ __align__(16) char smem[EK_SMEM];
    unsigned short* sE = (unsigned short*)(smem + EK_SE);
    unsigned short* sH = (unsigned short*)(smem + EK_SH);
    __shared__ int s_src[TME];
    __shared__ int s_dst[TME];
    __shared__ int s_eid[TME];

    const int tid  = threadIdx.x;
    const int wave = tid >> 6;
    const int lane = tid & 63;
    const int quad = lane >> 4;
    const int r16  = lane & 15;
    const int be0  = blockIdx.x * TME;

    if (tid < TME) {
        int eid = perm[be0 + tid];
        int b   = eid / E_EDGES;
        int2 se = ((const int2*)eidx)[eid];
        s_eid[tid] = eid;
        s_src[tid] = b * N_NODES + se.x;
        s_dst[tid] = b * N_NODES + se.y;
    }

    // GEMM1 weight fragments (k-rows 256..319 of W1m): issue early, overlap staging
    const unsigned short* wB1 = w1t + (size_t)(wave * 32) * K1 + 256;
    bf16x8 b00 = *(const bf16x8*)&wB1[(size_t)r16        * K1 + quad * 8];
    bf16x8 b01 = *(const bf16x8*)&wB1[(size_t)(16 + r16) * K1 + quad * 8];
    bf16x8 b10 = *(const bf16x8*)&wB1[(size_t)r16        * K1 + 32 + quad * 8];
    bf16x8 b11 = *(const bf16x8*)&wB1[(size_t)(16 + r16) * K1 + 32 + quad * 8];

    __syncthreads();   // s_eid visible

    // stage edge features fp32 -> bf16 panels: 2 x [64 rows x 32 k]
    {
        int row = tid >> 3;
        int c0  = (tid & 7) * 8;        // 0..56
        const float* fp = edgef + (size_t)s_eid[row] * ED + c0;
        float4 v0 = *(const float4*)fp;
        float4 v1 = *(const float4*)(fp + 4);
        ushort4 o0, o1;
        o0.x = f2bf(v0.x); o0.y = f2bf(v0.y); o0.z = f2bf(v0.z); o0.w = f2bf(v0.w);
        o1.x = f2bf(v1.x); o1.y = f2bf(v1.y); o1.z = f2bf(v1.z); o1.w = f2bf(v1.w);
        int p2 = c0 >> 5, kk = c0 & 31;
        *(ushort4*)&sE[p2 * 2048 + row * 32 + kk]     = o0;
        *(ushort4*)&sE[p2 * 2048 + row * 32 + kk + 4] = o1;
    }
    __syncthreads();

    f32x4 acc[4][2];
    #pragma unroll
    for (int mt = 0; mt < 4; ++mt)
        #pragma unroll
        for (int nt = 0; nt < 2; ++nt)
            acc[mt][nt] = (f32x4){0.f, 0.f, 0.f, 0.f};

    // ---- GEMM1: K=64 on edge features ----
    #pragma unroll
    for (int mt = 0; mt < 4; ++mt) {
        bf16x8 a0 = *(const bf16x8*)&sE[(mt * 16 + r16) * 32 + quad * 8];
        bf16x8 a1 = *(const bf16x8*)&sE[2048 + (mt * 16 + r16) * 32 + quad * 8];
        acc[mt][0] = __builtin_amdgcn_mfma_f32_16x16x32_bf16(a0, b00, acc[mt][0], 0, 0, 0);
        acc[mt][1] = __builtin_amdgcn_mfma_f32_16x16x32_bf16(a0, b01, acc[mt][1], 0, 0, 0);
        acc[mt][0] = __builtin_amdgcn_mfma_f32_16x16x32_bf16(a1, b10, acc[mt][0], 0, 0, 0);
        acc[mt][1] = __builtin_amdgcn_mfma_f32_16x16x32_bf16(a1, b11, acc[mt][1], 0, 0, 0);
    }

    // ---- gather-add epilogue: + P[src] + P[dst] + b1, gelu -> sH ----
    #pragma unroll
    for (int mt = 0; mt < 4; ++mt) {
        int m0 = mt * 16 + quad * 4;
        #pragma unroll
        for (int nt = 0; nt < 2; ++nt) {
            int n = wave * 32 + nt * 16 + r16;
            float bias = b1m[n];
            #pragma unroll
            for (int r = 0; r < 4; ++r) {
                float v = acc[mt][nt][r]
                        + g_P[(size_t)s_src[m0 + r] * 512 + n]
                        + g_P[(size_t)s_dst[m0 + r] * 512 + 256 + n]
                        + bias;
                sH[(m0 + r) * LDH + n] = f2bf(gelu_tanh(v));
            }
            acc[mt][nt] = (f32x4){0.f, 0.f, 0.f, 0.f};
        }
    }
    __syncthreads();   // sH visible to all waves

    // ---- GEMM2: K=256, weights global->VGPR one-step prefetch, no barriers ----
    {
        const unsigned short* wB = w2t + (size_t)(wave * 32) * K2;
        bf16x8 bc0 = *(const bf16x8*)&wB[(size_t)r16        * K2 + quad * 8];
        bf16x8 bc1 = *(const bf16x8*)&wB[(size_t)(16 + r16) * K2 + quad * 8];
        #pragma unroll
        for (int ks = 0; ks < K2 / 32; ++ks) {
            bf16x8 bn0 = bc0, bn1 = bc1;
            if (ks + 1 < K2 / 32) {
                bn0 = *(const bf16x8*)&wB[(size_t)r16        * K2 + (ks + 1) * 32 + quad * 8];
                bn1 = *(const bf16x8*)&wB[(size_t)(16 + r16) * K2 + (ks + 1) * 32 + quad * 8];
            }
            bf16x8 af[4];
            #pragma unroll
            for (int mt = 0; mt < 4; ++mt)
                af[mt] = *(const bf16x8*)&sH[(mt * 16 + r16) * LDH + ks * 32 + quad * 8];
            #pragma unroll
            for (int mt = 0; mt < 4; ++mt) {
                acc[mt][0] = __builtin_amdgcn_mfma_f32_16x16x32_bf16(
                    af[mt], bc0, acc[mt][0], 0, 0, 0);
                acc[mt][1] = __builtin_amdgcn_mfma_f32_16x16x32_bf16(
                    af[mt], bc1, acc[mt][1], 0, 0, 0);
            }
            bc0 = bn0; bc1 = bn1;
        }
    }
    __syncthreads();   // all waves done reading sH before fb overwrite

    // ---- epilogue: C2(+bias) -> fb (bf16, aliases sH), run-reduce ----
    unsigned short* fb = sH;
    #pragma unroll
    for (int nt = 0; nt < 2; ++nt) {
        int n = wave * 32 + nt * 16 + r16;
        float bias = b2m[n];
        #pragma unroll
        for (int mt = 0; mt < 4; ++mt) {
            #pragma unroll
            for (int r = 0; r < 4; ++r) {
                int m = mt * 16 + quad * 4 + r;
                fb[m * LDH + n] = f2bf(acc[mt][nt][r] + bias);
            }
        }
    }
    __syncthreads();

    {
        const int cc = tid & 255;          // column
        const int r0 = (tid >> 8) * 32;    // row-half base
        int   cur  = s_dst[r0];
        float racc = 0.f;
        for (int mb = 0; mb < 32; mb += 8) {
            float v[8];
            #pragma unroll
            for (int j = 0; j < 8; ++j)
                v[j] = bf2f(fb[(r0 + mb + j) * LDH + cc]);
            #pragma unroll
            for (int j = 0; j < 8; ++j) {
                int d = s_dst[r0 + mb + j];
                if (d != cur) {
                    atomicAdd(&agg[(size_t)cur * HID + cc], racc);
                    cur = d; racc = v[j];
                } else {
                    racc += v[j];
                }
            }
        }
        atomicAdd(&agg[(size_t)cur * HID + cc], racc);
    }
}

// ---------- node MLP (MFMA, barrier-free K-loops, LDS = sH only) ----------
// A fragments direct from global (rows contiguous): bf16 node part from g_nodef_bf,
// agg part cvt'd in regs. Weights (g_w1ut/g_w2ut, n-major) direct global->VGPR.
__global__ __launch_bounds__(256) void node_mlp_mfma(
    const float* __restrict__ agg,
    const float* __restrict__ b1u,
    const float* __restrict__ b2u,
    float* __restrict__ out)
{
    __shared__ __align__(16) unsigned short sH[TM * LDH];

    const int tid  = threadIdx.x;
    const int wave = tid >> 6;
    const int lane = tid & 63;
    const int quad = lane >> 4;
    const int r16  = lane & 15;
    const int n0   = blockIdx.x * TM;

    f32x4 acc[4][4];
    #pragma unroll
    for (int mt = 0; mt < 4; ++mt)
        #pragma unroll
        for (int nt = 0; nt < 4; ++nt)
            acc[mt][nt] = (f32x4){0.f, 0.f, 0.f, 0.f};

    // ---- L1 part A: k in [0,128) from g_nodef_bf ----
    for (int ks = 0; ks < 4; ++ks) {
        bf16x8 af[4], bfg[4];
        #pragma unroll
        for (int mt = 0; mt < 4; ++mt) {
            int row = n0 + mt * 16 + r16; if (row >= BN) row = BN - 1;
            af[mt] = *(const bf16x8*)&g_nodef_bf[(size_t)row * ND + ks * 32 + quad * 8];
        }
        #pragma unroll
        for (int nt = 0; nt < 4; ++nt)
            bfg[nt] = *(const bf16x8*)&g_w1ut[(size_t)(wave * 64 + nt * 16 + r16) * K1U
                                              + ks * 32 + quad * 8];
        #pragma unroll
        for (int mt = 0; mt < 4; ++mt)
            #pragma unroll
            for (int nt = 0; nt < 4; ++nt)
                acc[mt][nt] = __builtin_amdgcn_mfma_f32_16x16x32_bf16(
                    af[mt], bfg[nt], acc[mt][nt], 0, 0, 0);
    }
    // ---- L1 part B: k in [128,384) from agg (fp32 -> bf16 in regs) ----
    for (int ks = 0; ks < 8; ++ks) {
        bf16x8 af[4], bfg[4];
        #pragma unroll
        for (int mt = 0; mt < 4; ++mt) {
            int row = n0 + mt * 16 + r16; if (row >= BN) row = BN - 1;
            const float* fp = &agg[(size_t)row * HID + ks * 32 + quad * 8];
            float4 v0 = *(const float4*)fp;
            float4 v1 = *(const float4*)(fp + 4);
            union { bf16x8 v; ushort4 u[2]; } cv;
            cv.u[0] = (ushort4){f2bf(v0.x), f2bf(v0.y), f2bf(v0.z), f2bf(v0.w)};
            cv.u[1] = (ushort4){f2bf(v1.x), f2bf(v1.y), f2bf(v1.z), f2bf(v1.w)};
            af[mt] = cv.v;
        }
        #pragma unroll
        for (int nt = 0; nt < 4; ++nt)
            bfg[nt] = *(const bf16x8*)&g_w1ut[(size_t)(wave * 64 + nt * 16 + r16) * K1U
                                              + (4 + ks) * 32 + quad * 8];
        #pragma unroll
        for (int mt = 0; mt < 4; ++mt)
            #pragma unroll
            for (int nt = 0; nt < 4; ++nt)
                acc[mt][nt] = __builtin_amdgcn_mfma_f32_16x16x32_bf16(
                    af[mt], bfg[nt], acc[mt][nt], 0, 0, 0);
    }

    #pragma unroll
    for (int nt = 0; nt < 4; ++nt) {
        int n = wave * 64 + nt * 16 + r16;
        float bias = b1u[n];
        #pragma unroll
        for (int mt = 0; mt < 4; ++mt) {
            #pragma unroll
            for (int r = 0; r < 4; ++r) {
                int m = mt * 16 + quad * 4 + r;
                sH[m * LDH + n] = f2bf(gelu_tanh(acc[mt][nt][r] + bias));
            }
        }
    }
    __syncthreads();

    f32x4 acc2[4][2];
    #pragma unroll
    for (int mt = 0; mt < 4; ++mt)
        #pragma unroll
        for (int nt = 0; nt < 2; ++nt)
            acc2[mt][nt] = (f32x4){0.f, 0.f, 0.f, 0.f};

    for (int ks = 0; ks < K2 / 32; ++ks) {
        bf16x8 af[4], bfg[2];
        #pragma unroll
        for (int mt = 0; mt < 4; ++mt)
            af[mt] = *(const bf16x8*)&sH[(mt * 16 + r16) * LDH + ks * 32 + quad * 8];
        #pragma unroll
        for (int nt = 0; nt < 2; ++nt)
            bfg[nt] = *(const bf16x8*)&g_w2ut[(size_t)(wave * 32 + nt * 16 + r16) * K2
                                              + ks * 32 + quad * 8];
        #pragma unroll
        for (int mt = 0; mt < 4; ++mt)
            #pragma unroll
            for (int nt = 0; nt < 2; ++nt)
                acc2[mt][nt] = __builtin_amdgcn_mfma_f32_16x16x32_bf16(
                    af[mt], bfg[nt], acc2[mt][nt], 0, 0, 0);
    }

    #pragma unroll
    for (int nt = 0; nt < 2; ++nt) {
        int n = wave * 32 + nt * 16 + r16;
        float bias = b2u[n];
        #pragma unroll
        for (int mt = 0; mt < 4; ++mt) {
            #pragma unroll
            for (int r = 0; r < 4; ++r) {
                int m = mt * 16 + quad * 4 + r;
                if (n0 + m < BN)
                    out[(size_t)(n0 + m) * NOUT + n] = acc2[mt][nt][r] + bias;
            }
        }
    }
}

// ---------- launch ----------
// ws: agg [0 .. 20,480,000) (proven).
// d_out stash (read only before node_mlp_mfma runs):
//   w1t      [5,120,000 .. 5,283,840)
//   w2t      [5,283,840 .. 5,414,912)
//   hist     [5,414,912 .. 5,494,912)
//   offs     [5,494,912 .. 5,574,912)
//   perm     [5,574,912 .. 6,854,912)
//   bsum     [6,854,912 .. 6,855,040)
// Everything else lives in __device__ statics (g_P, g_nodef_bf, g_w1ut, g_w2ut).

extern "C" void kernel_launch(void* const* d_in, const int* in_sizes, int n_in,
                              void* d_out, int out_size, void* d_ws, size_t ws_size,
                              hipStream_t stream) {
    const float* nodef = (const float*)d_in[0];
    const int*   eidx  = (const int*)  d_in[1];
    const float* edgef = (const float*)d_in[2];
    const float* W1m   = (const float*)d_in[3];
    const float* b1m   = (const float*)d_in[4];
    const float* W2m   = (const float*)d_in[5];
    const float* b2m   = (const float*)d_in[6];
    const float* W1u   = (const float*)d_in[7];
    const float* b1u   = (const float*)d_in[8];
    const float* W2u   = (const float*)d_in[9];
    const float* b2u   = (const float*)d_in[10];
    float* out = (float*)d_out;

    char* wsb = (char*)d_ws;
    float* agg = (float*)wsb;
    const size_t AGG_B = (size_t)BN * HID * sizeof(float);

    char* ob = (char*)d_out;
    unsigned short* w1t  = (unsigned short*)(ob + 5120000);
    unsigned short* w2t  = (unsigned short*)(ob + 5283840);
    int* hist            = (int*)(ob + 5414912);
    int* offs            = (int*)(ob + 5494912);
    int* perm            = (int*)(ob + 5574912);
    int* bsum            = (int*)(ob + 6854912);

    hipMemsetAsync(agg, 0, AGG_B, stream);
    hipMemsetAsync(hist, 0, BN * sizeof(int), stream);

    {
        int n4 = BN * ND / 4;
        f32_to_bf16_vec<<<(n4 + 255) / 256, 256, 0, stream>>>(nodef, n4);
    }
    w_transpose_bf16<<<(K1 * HID + 255) / 256, 256, 0, stream>>>(W1m, w1t, K1, HID);
    w_transpose_bf16<<<(K2 * HID + 255) / 256, 256, 0, stream>>>(W2m, w2t, K2, HID);
    prep_upd_weights<<<(K1U * HID + 255) / 256, 256, 0, stream>>>(W1u, W2u);

    pgemm<<<(BN + TM - 1) / TM, 512, 0, stream>>>(w1t);

    dst_hist<<<(BE + 255) / 256, 256, 0, stream>>>(eidx, hist);
    scan_partial<<<SCAN_BLOCKS, 1024, 0, stream>>>(hist, offs, bsum);
    scan_sums<<<1, 64, 0, stream>>>(bsum);
    scan_add<<<SCAN_BLOCKS, 1024, 0, stream>>>(offs, bsum);
    dst_scatter<<<(BE + 255) / 256, 256, 0, stream>>>(eidx, offs, perm);

    edge_mlp_mfma<<<BE / TME, 512, 0, stream>>>(
        eidx, edgef, perm, w1t, b1m, w2t, b2m, agg);

    node_mlp_mfma<<<(BN + TM - 1) / TM, 256, 0, stream>>>(agg, b1u, b2u, out);
}

// Round 3
// 413.951 us; speedup vs baseline: 1.0201x; 1.0201x over previous
//
#include <hip/hip_runtime.h>
#include <hip/hip_bf16.h>
#include <math.h>

#define BATCH   2
#define N_NODES 10000
#define E_EDGES 160000
#define BN      (BATCH * N_NODES)       // 20000
#define BE      (BATCH * E_EDGES)       // 320000
#define ND      128
#define ED      64
#define HID     256
#define K1      320   // 2*ND + ED
#define K2      256
#define K1U     384   // ND + HID
#define NOUT    128
#define TM      64    // node-kernel rows per block
#define TME     64    // edge-kernel rows per block
#define LDH     264   // H stride (bf16), 256+8
#define SCAN_BLOCKS ((BN + 1023) / 1024)   // 20

typedef __attribute__((ext_vector_type(8))) short bf16x8;
typedef __attribute__((ext_vector_type(4))) float f32x4;

// ---------- static device buffers ----------
__device__ float          g_P[(size_t)BN * 512];        // [n][0:256)=src-part, [256:512)=dst-part
__device__ unsigned short g_nodef_bf[(size_t)BN * ND];  // bf16 node features
__device__ unsigned short g_w1ut[K1U * HID];            // node L1 weights, n-major bf16
__device__ unsigned short g_w2ut[K2 * NOUT];            // node L2 weights, n-major bf16

// fast tanh-gelu: tanh(u) = 1 - 2/(exp(2u)+1); both tails saturate correctly.
__device__ __forceinline__ float gelu_tanh(float x) {
    float u = 0.7978845608028654f * (x + 0.044715f * x * x * x);
    float e = __expf(2.0f * u);
    float t = 1.0f - 2.0f * __builtin_amdgcn_rcpf(e + 1.0f);
    return 0.5f * x * (1.0f + t);
}

__device__ __forceinline__ unsigned short f2bf(float f) {
    __hip_bfloat16 h = __float2bfloat16(f);
    return *reinterpret_cast<unsigned short*>(&h);
}

__device__ __forceinline__ float bf2f(unsigned short u) {
    unsigned int x = ((unsigned int)u) << 16;
    return *reinterpret_cast<float*>(&x);
}

// ---------- prep kernels ----------

__global__ __launch_bounds__(256) void f32_to_bf16_vec(
    const float* __restrict__ in, int n4)
{
    int i = blockIdx.x * blockDim.x + threadIdx.x;
    if (i < n4) {
        float4 v = ((const float4*)in)[i];
        ushort4 o;
        o.x = f2bf(v.x); o.y = f2bf(v.y); o.z = f2bf(v.z); o.w = f2bf(v.w);
        ((ushort4*)g_nodef_bf)[i] = o;
    }
}

// merged weight prep: W1m->w1t, W2m->w2t, W1u->g_w1ut, W2u->g_w2ut (all n-major bf16)
__global__ __launch_bounds__(256) void prep_weights(
    const float* __restrict__ W1m, unsigned short* __restrict__ w1t,
    const float* __restrict__ W2m, unsigned short* __restrict__ w2t,
    const float* __restrict__ W1u, const float* __restrict__ W2u)
{
    int id = blockIdx.x * blockDim.x + threadIdx.x;
    if (id < K1 * HID) {
        int k = id % K1, n = id / K1;
        w1t[id] = f2bf(W1m[(size_t)k * HID + n]);
    }
    if (id < K2 * HID) {
        int k = id % K2, n = id / K2;
        w2t[id] = f2bf(W2m[(size_t)k * HID + n]);
    }
    if (id < K1U * HID) {
        int k = id % K1U, n = id / K1U;
        g_w1ut[id] = f2bf(W1u[(size_t)k * HID + n]);
    }
    if (id < K2 * NOUT) {
        int k = id % K2, n = id / K2;
        g_w2ut[id] = f2bf(W2u[(size_t)k * NOUT + n]);
    }
}

__global__ __launch_bounds__(256) void dst_hist(
    const int* __restrict__ eidx, int* __restrict__ hist)
{
    int e = blockIdx.x * blockDim.x + threadIdx.x;
    if (e < BE) {
        int dst = eidx[2 * e + 1];
        int b   = e / E_EDGES;
        atomicAdd(&hist[b * N_NODES + dst], 1);
    }
}

// ---------- hierarchical scan ----------

__global__ __launch_bounds__(1024) void scan_partial(
    const int* __restrict__ hist, int* __restrict__ offs, int* __restrict__ bsum)
{
    __shared__ int buf[1024];
    int tid = threadIdx.x;
    int i   = blockIdx.x * 1024 + tid;
    int v   = (i < BN) ? hist[i] : 0;
    buf[tid] = v;
    __syncthreads();
    #pragma unroll
    for (int d = 1; d < 1024; d <<= 1) {
        int t = (tid >= d) ? buf[tid - d] : 0;
        __syncthreads();
        buf[tid] += t;
        __syncthreads();
    }
    int incl = buf[tid];
    if (i < BN) offs[i] = incl - v;
    if (tid == 1023) bsum[blockIdx.x] = incl;
}

// scan_add with inline 20-element bsum prefix (kills the scan_sums launch)
__global__ __launch_bounds__(1024) void scan_add(
    int* __restrict__ offs, const int* __restrict__ bsum)
{
    __shared__ int sbase;
    int tid = threadIdx.x;
    if (tid < 64) {
        int v = (tid < blockIdx.x && tid < SCAN_BLOCKS) ? bsum[tid] : 0;
        #pragma unroll
        for (int d = 32; d > 0; d >>= 1) v += __shfl_down(v, d);
        if (tid == 0) sbase = v;
    }
    __syncthreads();
    int i = blockIdx.x * 1024 + tid;
    if (i < BN) offs[i] += sbase;
}

__global__ __launch_bounds__(256) void dst_scatter(
    const int* __restrict__ eidx, int* __restrict__ offs, int* __restrict__ perm)
{
    int e = blockIdx.x * blockDim.x + threadIdx.x;
    if (e < BE) {
        int dst  = eidx[2 * e + 1];
        int b    = e / E_EDGES;
        int pos  = atomicAdd(&offs[b * N_NODES + dst], 1);
        perm[pos] = e;
    }
}

// ---------- P GEMM: g_P[n][0:512) = nodef_bf @ [W1m[0:128] | W1m[128:256]] ----------
// Transposed-operand MFMA: A=weight n-rows, B=node rows -> lane holds one node row
// x 4 consecutive output cols -> float4 stores.
__global__ __launch_bounds__(512, 2) void pgemm(const unsigned short* __restrict__ w1t)
{
    const int tid  = threadIdx.x;
    const int wave = tid >> 6;
    const int lane = tid & 63;
    const int quad = lane >> 4;
    const int r16  = lane & 15;
    const int n0   = blockIdx.x * TM;

    const int jb   = (wave & 3) * 64;              // col base within 256
    const int koff = (wave < 4) ? 0 : 128;         // W1m k-row offset
    const int cb   = (wave < 4) ? 0 : 256;         // output col-base add

    f32x4 acc[4][4];
    #pragma unroll
    for (int mt = 0; mt < 4; ++mt)
        #pragma unroll
        for (int nt = 0; nt < 4; ++nt)
            acc[mt][nt] = (f32x4){0.f, 0.f, 0.f, 0.f};

    for (int ks = 0; ks < ND / 32; ++ks) {
        bf16x8 wf[4], nf[4];
        #pragma unroll
        for (int nt = 0; nt < 4; ++nt)
            wf[nt] = *(const bf16x8*)&w1t[(size_t)(jb + nt * 16 + r16) * K1
                                          + koff + ks * 32 + quad * 8];
        #pragma unroll
        for (int mt = 0; mt < 4; ++mt) {
            int row = n0 + mt * 16 + r16; if (row >= BN) row = BN - 1;
            nf[mt] = *(const bf16x8*)&g_nodef_bf[(size_t)row * ND + ks * 32 + quad * 8];
        }
        #pragma unroll
        for (int mt = 0; mt < 4; ++mt)
            #pragma unroll
            for (int nt = 0; nt < 4; ++nt)
                acc[mt][nt] = __builtin_amdgcn_mfma_f32_16x16x32_bf16(
                    wf[nt], nf[mt], acc[mt][nt], 0, 0, 0);
    }

    #pragma unroll
    for (int nt = 0; nt < 4; ++nt) {
        int j0 = cb + jb + nt * 16 + quad * 4;
        #pragma unroll
        for (int mt = 0; mt < 4; ++mt) {
            int m = n0 + mt * 16 + r16;
            if (m < BN) {
                float4 v = {acc[mt][nt][0], acc[mt][nt][1],
                            acc[mt][nt][2], acc[mt][nt][3]};
                *(float4*)&g_P[(size_t)m * 512 + j0] = v;
            }
        }
    }
}

// ---------- edge MLP ----------
// Transposed-operand MFMA throughout: lane holds edge row m = mtile*16 + (lane&15),
// 4 consecutive n per (nt). P gather/bias/sH stores all vectorized.
// LDS 41,984 B (+768 idx) -> 3 blocks/CU.
#define EK_SE   0
#define EK_SH   8192
#define EK_SMEM (8192 + TME * LDH * 2)   // 41,984

__global__ __launch_bounds__(512, 6) void edge_mlp_mfma(
    const int*            __restrict__ eidx,
    const float*          __restrict__ edgef,
    const int*            __restrict__ perm,
    const unsigned short* __restrict__ w1t,       // [256][320] bf16 n-major
    const float*          __restrict__ b1m,
    const unsigned short* __restrict__ w2t,       // [256][256] bf16 n-major
    const float*          __restrict__ b2m,
    float* __restrict__ agg)
{
    __shared__ __align__(16) char smem[EK_SMEM];
    unsigned short* sE = (unsigned short*)(smem + EK_SE);
    unsigned short* sH = (unsigned short*)(smem + EK_SH);
    __shared__ int s_src[TME];
    __shared__ int s_dst[TME];
    __shared__ int s_eid[TME];

    const int tid  = threadIdx.x;
    const int wave = tid >> 6;
    const int lane = tid & 63;
    const int quad = lane >> 4;
    const int r16  = lane & 15;
    const int be0  = blockIdx.x * TME;

    if (tid < TME) {
        int eid = perm[be0 + tid];
        int b   = eid / E_EDGES;
        int2 se = ((const int2*)eidx)[eid];
        s_eid[tid] = eid;
        s_src[tid] = b * N_NODES + se.x;
        s_dst[tid] = b * N_NODES + se.y;
    }

    // GEMM1 weight A-frags (k-rows 256..319 of W1m): issue early, overlap staging.
    // wf[nt][ks]: n-rows wave*32+nt*16+[0,16), k-chunk 256+ks*32.
    const unsigned short* wB1 = w1t + (size_t)(wave * 32) * K1 + 256;
    bf16x8 wf00 = *(const bf16x8*)&wB1[(size_t)r16        * K1 + quad * 8];
    bf16x8 wf01 = *(const bf16x8*)&wB1[(size_t)r16        * K1 + 32 + quad * 8];
    bf16x8 wf10 = *(const bf16x8*)&wB1[(size_t)(16 + r16) * K1 + quad * 8];
    bf16x8 wf11 = *(const bf16x8*)&wB1[(size_t)(16 + r16) * K1 + 32 + quad * 8];

    __syncthreads();   // s_eid visible

    // stage edge features fp32 -> bf16 panels: 2 x [64 rows x 32 k]
    {
        int row = tid >> 3;
        int c0  = (tid & 7) * 8;        // 0..56
        const float* fp = edgef + (size_t)s_eid[row] * ED + c0;
        float4 v0 = *(const float4*)fp;
        float4 v1 = *(const float4*)(fp + 4);
        ushort4 o0, o1;
        o0.x = f2bf(v0.x); o0.y = f2bf(v0.y); o0.z = f2bf(v0.z); o0.w = f2bf(v0.w);
        o1.x = f2bf(v1.x); o1.y = f2bf(v1.y); o1.z = f2bf(v1.z); o1.w = f2bf(v1.w);
        int p2 = c0 >> 5, kk = c0 & 31;
        *(ushort4*)&sE[p2 * 2048 + row * 32 + kk]     = o0;
        *(ushort4*)&sE[p2 * 2048 + row * 32 + kk + 4] = o1;
    }
    __syncthreads();

    f32x4 acc[4][2];
    #pragma unroll
    for (int mt = 0; mt < 4; ++mt)
        #pragma unroll
        for (int nt = 0; nt < 2; ++nt)
            acc[mt][nt] = (f32x4){0.f, 0.f, 0.f, 0.f};

    // ---- GEMM1: K=64 on edge features (A=weights, B=edge rows) ----
    #pragma unroll
    for (int mt = 0; mt < 4; ++mt) {
        bf16x8 e0 = *(const bf16x8*)&sE[(mt * 16 + r16) * 32 + quad * 8];
        bf16x8 e1 = *(const bf16x8*)&sE[2048 + (mt * 16 + r16) * 32 + quad * 8];
        acc[mt][0] = __builtin_amdgcn_mfma_f32_16x16x32_bf16(wf00, e0, acc[mt][0], 0, 0, 0);
        acc[mt][1] = __builtin_amdgcn_mfma_f32_16x16x32_bf16(wf10, e0, acc[mt][1], 0, 0, 0);
        acc[mt][0] = __builtin_amdgcn_mfma_f32_16x16x32_bf16(wf01, e1, acc[mt][0], 0, 0, 0);
        acc[mt][1] = __builtin_amdgcn_mfma_f32_16x16x32_bf16(wf11, e1, acc[mt][1], 0, 0, 0);
    }

    // ---- gather-add epilogue: + P[src] + P[dst] + b1, gelu -> sH (all float4) ----
    {
        float4 bb[2];
        bb[0] = *(const float4*)&b1m[wave * 32 + quad * 4];
        bb[1] = *(const float4*)&b1m[wave * 32 + 16 + quad * 4];
        #pragma unroll
        for (int mt = 0; mt < 4; ++mt) {
            int m = mt * 16 + r16;
            const float* pS = &g_P[(size_t)s_src[m] * 512];
            const float* pD = &g_P[(size_t)s_dst[m] * 512 + 256];
            #pragma unroll
            for (int nt = 0; nt < 2; ++nt) {
                int n0 = wave * 32 + nt * 16 + quad * 4;
                float4 vs = *(const float4*)(pS + n0);
                float4 vd = *(const float4*)(pD + n0);
                ushort4 o;
                o.x = f2bf(gelu_tanh(acc[mt][nt][0] + vs.x + vd.x + bb[nt].x));
                o.y = f2bf(gelu_tanh(acc[mt][nt][1] + vs.y + vd.y + bb[nt].y));
                o.z = f2bf(gelu_tanh(acc[mt][nt][2] + vs.z + vd.z + bb[nt].z));
                o.w = f2bf(gelu_tanh(acc[mt][nt][3] + vs.w + vd.w + bb[nt].w));
                *(ushort4*)&sH[m * LDH + n0] = o;
                acc[mt][nt] = (f32x4){0.f, 0.f, 0.f, 0.f};
            }
        }
    }
    __syncthreads();   // sH visible to all waves

    // ---- GEMM2: K=256 (A=w2 rows global->VGPR prefetch, B=sH rows), no barriers ----
    {
        const unsigned short* wB = w2t + (size_t)(wave * 32) * K2;
        bf16x8 bc0 = *(const bf16x8*)&wB[(size_t)r16        * K2 + quad * 8];
        bf16x8 bc1 = *(const bf16x8*)&wB[(size_t)(16 + r16) * K2 + quad * 8];
        #pragma unroll
        for (int ks = 0; ks < K2 / 32; ++ks) {
            bf16x8 bn0 = bc0, bn1 = bc1;
            if (ks + 1 < K2 / 32) {
                bn0 = *(const bf16x8*)&wB[(size_t)r16        * K2 + (ks + 1) * 32 + quad * 8];
                bn1 = *(const bf16x8*)&wB[(size_t)(16 + r16) * K2 + (ks + 1) * 32 + quad * 8];
            }
            bf16x8 hf[4];
            #pragma unroll
            for (int mt = 0; mt < 4; ++mt)
                hf[mt] = *(const bf16x8*)&sH[(mt * 16 + r16) * LDH + ks * 32 + quad * 8];
            #pragma unroll
            for (int mt = 0; mt < 4; ++mt) {
                acc[mt][0] = __builtin_amdgcn_mfma_f32_16x16x32_bf16(
                    bc0, hf[mt], acc[mt][0], 0, 0, 0);
                acc[mt][1] = __builtin_amdgcn_mfma_f32_16x16x32_bf16(
                    bc1, hf[mt], acc[mt][1], 0, 0, 0);
            }
            bc0 = bn0; bc1 = bn1;
        }
    }
    __syncthreads();   // all waves done reading sH before fb overwrite

    // ---- epilogue: C2(+bias) -> fb (bf16, aliases sH), vectorized ----
    unsigned short* fb = sH;
    {
        float4 bb[2];
        bb[0] = *(const float4*)&b2m[wave * 32 + quad * 4];
        bb[1] = *(const float4*)&b2m[wave * 32 + 16 + quad * 4];
        #pragma unroll
        for (int mt = 0; mt < 4; ++mt) {
            int m = mt * 16 + r16;
            #pragma unroll
            for (int nt = 0; nt < 2; ++nt) {
                int n0 = wave * 32 + nt * 16 + quad * 4;
                ushort4 o;
                o.x = f2bf(acc[mt][nt][0] + bb[nt].x);
                o.y = f2bf(acc[mt][nt][1] + bb[nt].y);
                o.z = f2bf(acc[mt][nt][2] + bb[nt].z);
                o.w = f2bf(acc[mt][nt][3] + bb[nt].w);
                *(ushort4*)&fb[m * LDH + n0] = o;
            }
        }
    }
    __syncthreads();

    {
        const int cc = tid & 255;          // column
        const int r0 = (tid >> 8) * 32;    // row-half base
        int   cur  = s_dst[r0];
        float racc = 0.f;
        for (int mb = 0; mb < 32; mb += 8) {
            float v[8];
            #pragma unroll
            for (int j = 0; j < 8; ++j)
                v[j] = bf2f(fb[(r0 + mb + j) * LDH + cc]);
            #pragma unroll
            for (int j = 0; j < 8; ++j) {
                int d = s_dst[r0 + mb + j];
                if (d != cur) {
                    atomicAdd(&agg[(size_t)cur * HID + cc], racc);
                    cur = d; racc = v[j];
                } else {
                    racc += v[j];
                }
            }
        }
        atomicAdd(&agg[(size_t)cur * HID + cc], racc);
    }
}

// ---------- node MLP (transposed-operand MFMA, vectorized epilogues) ----------
__global__ __launch_bounds__(256) void node_mlp_mfma(
    const float* __restrict__ agg,
    const float* __restrict__ b1u,
    const float* __restrict__ b2u,
    float* __restrict__ out)
{
    __shared__ __align__(16) unsigned short sH[TM * LDH];

    const int tid  = threadIdx.x;
    const int wave = tid >> 6;
    const int lane = tid & 63;
    const int quad = lane >> 4;
    const int r16  = lane & 15;
    const int n0   = blockIdx.x * TM;

    f32x4 acc[4][4];
    #pragma unroll
    for (int mt = 0; mt < 4; ++mt)
        #pragma unroll
        for (int nt = 0; nt < 4; ++nt)
            acc[mt][nt] = (f32x4){0.f, 0.f, 0.f, 0.f};

    // ---- L1 part A: k in [0,128) from g_nodef_bf ----
    for (int ks = 0; ks < 4; ++ks) {
        bf16x8 wf[4], nf[4];
        #pragma unroll
        for (int nt = 0; nt < 4; ++nt)
            wf[nt] = *(const bf16x8*)&g_w1ut[(size_t)(wave * 64 + nt * 16 + r16) * K1U
                                             + ks * 32 + quad * 8];
        #pragma unroll
        for (int mt = 0; mt < 4; ++mt) {
            int row = n0 + mt * 16 + r16; if (row >= BN) row = BN - 1;
            nf[mt] = *(const bf16x8*)&g_nodef_bf[(size_t)row * ND + ks * 32 + quad * 8];
        }
        #pragma unroll
        for (int mt = 0; mt < 4; ++mt)
            #pragma unroll
            for (int nt = 0; nt < 4; ++nt)
                acc[mt][nt] = __builtin_amdgcn_mfma_f32_16x16x32_bf16(
                    wf[nt], nf[mt], acc[mt][nt], 0, 0, 0);
    }
    // ---- L1 part B: k in [128,384) from agg (fp32 -> bf16 in regs) ----
    for (int ks = 0; ks < 8; ++ks) {
        bf16x8 wf[4], nf[4];
        #pragma unroll
        for (int nt = 0; nt < 4; ++nt)
            wf[nt] = *(const bf16x8*)&g_w1ut[(size_t)(wave * 64 + nt * 16 + r16) * K1U
                                             + (4 + ks) * 32 + quad * 8];
        #pragma unroll
        for (int mt = 0; mt < 4; ++mt) {
            int row = n0 + mt * 16 + r16; if (row >= BN) row = BN - 1;
            const float* fp = &agg[(size_t)row * HID + ks * 32 + quad * 8];
            float4 v0 = *(const float4*)fp;
            float4 v1 = *(const float4*)(fp + 4);
            union { bf16x8 v; ushort4 u[2]; } cv;
            cv.u[0] = (ushort4){f2bf(v0.x), f2bf(v0.y), f2bf(v0.z), f2bf(v0.w)};
            cv.u[1] = (ushort4){f2bf(v1.x), f2bf(v1.y), f2bf(v1.z), f2bf(v1.w)};
            nf[mt] = cv.v;
        }
        #pragma unroll
        for (int mt = 0; mt < 4; ++mt)
            #pragma unroll
            for (int nt = 0; nt < 4; ++nt)
                acc[mt][nt] = __builtin_amdgcn_mfma_f32_16x16x32_bf16(
                    wf[nt], nf[mt], acc[mt][nt], 0, 0, 0);
    }

    // ---- L1 epilogue -> sH (ushort4 stores) ----
    #pragma unroll
    for (int nt = 0; nt < 4; ++nt) {
        int nn0 = wave * 64 + nt * 16 + quad * 4;
        float4 bb = *(const float4*)&b1u[nn0];
        #pragma unroll
        for (int mt = 0; mt < 4; ++mt) {
            int m = mt * 16 + r16;
            ushort4 o;
            o.x = f2bf(gelu_tanh(acc[mt][nt][0] + bb.x));
            o.y = f2bf(gelu_tanh(acc[mt][nt][1] + bb.y));
            o.z = f2bf(gelu_tanh(acc[mt][nt][2] + bb.z));
            o.w = f2bf(gelu_tanh(acc[mt][nt][3] + bb.w));
            *(ushort4*)&sH[m * LDH + nn0] = o;
        }
    }
    __syncthreads();

    f32x4 acc2[4][2];
    #pragma unroll
    for (int mt = 0; mt < 4; ++mt)
        #pragma unroll
        for (int nt = 0; nt < 2; ++nt)
            acc2[mt][nt] = (f32x4){0.f, 0.f, 0.f, 0.f};

    for (int ks = 0; ks < K2 / 32; ++ks) {
        bf16x8 wf2[2], hf[4];
        #pragma unroll
        for (int nt = 0; nt < 2; ++nt)
            wf2[nt] = *(const bf16x8*)&g_w2ut[(size_t)(wave * 32 + nt * 16 + r16) * K2
                                              + ks * 32 + quad * 8];
        #pragma unroll
        for (int mt = 0; mt < 4; ++mt)
            hf[mt] = *(const bf16x8*)&sH[(mt * 16 + r16) * LDH + ks * 32 + quad * 8];
        #pragma unroll
        for (int mt = 0; mt < 4; ++mt)
            #pragma unroll
            for (int nt = 0; nt < 2; ++nt)
                acc2[mt][nt] = __builtin_amdgcn_mfma_f32_16x16x32_bf16(
                    wf2[nt], hf[mt], acc2[mt][nt], 0, 0, 0);
    }

    // ---- L2 epilogue -> out (float4 stores) ----
    #pragma unroll
    for (int nt = 0; nt < 2; ++nt) {
        int j0 = wave * 32 + nt * 16 + quad * 4;
        float4 bb = *(const float4*)&b2u[j0];
        #pragma unroll
        for (int mt = 0; mt < 4; ++mt) {
            int row = n0 + mt * 16 + r16;
            if (row < BN) {
                float4 v = {acc2[mt][nt][0] + bb.x, acc2[mt][nt][1] + bb.y,
                            acc2[mt][nt][2] + bb.z, acc2[mt][nt][3] + bb.w};
                *(float4*)&out[(size_t)row * NOUT + j0] = v;
            }
        }
    }
}

// ---------- launch ----------
// ws: agg [0 .. 20,480,000). d_out stash (read only before node_mlp_mfma runs):
//   w1t  [5,120,000 .. 5,283,840)
//   w2t  [5,283,840 .. 5,414,912)
//   hist [5,414,912 .. 5,494,912)
//   offs [5,494,912 .. 5,574,912)
//   perm [5,574,912 .. 6,854,912)
//   bsum [6,854,912 .. 6,855,040)

extern "C" void kernel_launch(void* const* d_in, const int* in_sizes, int n_in,
                              void* d_out, int out_size, void* d_ws, size_t ws_size,
                              hipStream_t stream) {
    const float* nodef = (const float*)d_in[0];
    const int*   eidx  = (const int*)  d_in[1];
    const float* edgef = (const float*)d_in[2];
    const float* W1m   = (const float*)d_in[3];
    const float* b1m   = (const float*)d_in[4];
    const float* W2m   = (const float*)d_in[5];
    const float* b2m   = (const float*)d_in[6];
    const float* W1u   = (const float*)d_in[7];
    const float* b1u   = (const float*)d_in[8];
    const float* W2u   = (const float*)d_in[9];
    const float* b2u   = (const float*)d_in[10];
    float* out = (float*)d_out;

    char* wsb = (char*)d_ws;
    float* agg = (float*)wsb;
    const size_t AGG_B = (size_t)BN * HID * sizeof(float);

    char* ob = (char*)d_out;
    unsigned short* w1t  = (unsigned short*)(ob + 5120000);
    unsigned short* w2t  = (unsigned short*)(ob + 5283840);
    int* hist            = (int*)(ob + 5414912);
    int* offs            = (int*)(ob + 5494912);
    int* perm            = (int*)(ob + 5574912);
    int* bsum            = (int*)(ob + 6854912);

    hipMemsetAsync(agg, 0, AGG_B, stream);
    hipMemsetAsync(hist, 0, BN * sizeof(int), stream);

    {
        int n4 = BN * ND / 4;
        f32_to_bf16_vec<<<(n4 + 255) / 256, 256, 0, stream>>>(nodef, n4);
    }
    prep_weights<<<(K1U * HID + 255) / 256, 256, 0, stream>>>(
        W1m, w1t, W2m, w2t, W1u, W2u);

    pgemm<<<(BN + TM - 1) / TM, 512, 0, stream>>>(w1t);

    dst_hist<<<(BE + 255) / 256, 256, 0, stream>>>(eidx, hist);
    scan_partial<<<SCAN_BLOCKS, 1024, 0, stream>>>(hist, offs, bsum);
    scan_add<<<SCAN_BLOCKS, 1024, 0, stream>>>(offs, bsum);
    dst_scatter<<<(BE + 255) / 256, 256, 0, stream>>>(eidx, offs, perm);

    edge_mlp_mfma<<<BE / TME, 512, 0, stream>>>(
        eidx, edgef, perm, w1t, b1m, w2t, b2m, agg);

    node_mlp_mfma<<<(BN + TM - 1) / TM, 256, 0, stream>>>(agg, b1u, b2u, out);
}

// Round 4
// 365.484 us; speedup vs baseline: 1.1554x; 1.1326x over previous
//
#include <hip/hip_runtime.h>
#include <hip/hip_bf16.h>
#include <math.h>

#define BATCH   2
#define N_NODES 10000
#define E_EDGES 160000
#define BN      (BATCH * N_NODES)       // 20000
#define BE      (BATCH * E_EDGES)       // 320000
#define ND      128
#define ED      64
#define HID     256
#define K1      320   // 2*ND + ED
#define K2      256
#define K1U     384   // ND + HID
#define NOUT    128
#define TM      64    // node-kernel rows per block
#define TME     64    // edge-kernel rows per block
#define LDH     264   // H stride (bf16), 256+8
#define SCAN_BLOCKS ((BN + 1023) / 1024)   // 20

typedef __attribute__((ext_vector_type(8))) short bf16x8;
typedef __attribute__((ext_vector_type(4))) float f32x4;

// ---------- static device buffers ----------
__device__ float          g_P[(size_t)BN * 512];        // [n][0:256)=src-part, [256:512)=dst-part
__device__ unsigned short g_nodef_bf[(size_t)BN * ND];  // bf16 node features
__device__ unsigned short g_w1c[HID * K1U];             // node L1 weights n-major bf16:
                                                        //   cols [0,128)  = W1u[0:128]^T
                                                        //   cols [128,384)= (W2m @ W1u[128:384])^T
__device__ unsigned short g_w2ut[K2 * NOUT];            // node L2 weights, n-major bf16
__device__ float          g_bc[HID];                    // b2m @ W1u[128:384]
__device__ int            g_hist[BN];                   // per-dst edge counts

// fast tanh-gelu: tanh(u) = 1 - 2/(exp(2u)+1); both tails saturate correctly.
__device__ __forceinline__ float gelu_tanh(float x) {
    float u = 0.7978845608028654f * (x + 0.044715f * x * x * x);
    float e = __expf(2.0f * u);
    float t = 1.0f - 2.0f * __builtin_amdgcn_rcpf(e + 1.0f);
    return 0.5f * x * (1.0f + t);
}

__device__ __forceinline__ unsigned short f2bf(float f) {
    __hip_bfloat16 h = __float2bfloat16(f);
    return *reinterpret_cast<unsigned short*>(&h);
}

__device__ __forceinline__ float bf2f(unsigned short u) {
    unsigned int x = ((unsigned int)u) << 16;
    return *reinterpret_cast<float*>(&x);
}

// ---------- prep kernels ----------

// also zeroes g_hist (runs before dst_hist in-stream)
__global__ __launch_bounds__(256) void f32_to_bf16_vec(
    const float* __restrict__ in, int n4)
{
    int i = blockIdx.x * blockDim.x + threadIdx.x;
    if (i < n4) {
        float4 v = ((const float4*)in)[i];
        ushort4 o;
        o.x = f2bf(v.x); o.y = f2bf(v.y); o.z = f2bf(v.z); o.w = f2bf(v.w);
        ((ushort4*)g_nodef_bf)[i] = o;
    }
    if (i < BN) g_hist[i] = 0;
}

// W1m->w1t; W1u[0:128]->g_w1c cols 0..127; W2u->g_w2ut
__global__ __launch_bounds__(256) void prep_weights(
    const float* __restrict__ W1m, unsigned short* __restrict__ w1t,
    const float* __restrict__ W1u, const float* __restrict__ W2u)
{
    int id = blockIdx.x * blockDim.x + threadIdx.x;
    if (id < K1 * HID) {
        int k = id % K1, n = id / K1;
        w1t[id] = f2bf(W1m[(size_t)k * HID + n]);
    }
    if (id < ND * HID) {
        int k = id % ND, n = id / ND;
        g_w1c[n * K1U + k] = f2bf(W1u[(size_t)k * HID + n]);
    }
    if (id < K2 * NOUT) {
        int k = id % K2, n = id / K2;
        g_w2ut[id] = f2bf(W2u[(size_t)k * NOUT + n]);
    }
}

// Wc[j][n] = sum_o W2m[j][o] * W1u[128+o][n]  -> g_w1c[n][128+j]
// bc[n]    = sum_o b2m[o]    * W1u[128+o][n]  -> g_bc[n]
__global__ __launch_bounds__(256) void prep_wc(
    const float* __restrict__ W2m, const float* __restrict__ W1u,
    const float* __restrict__ b2m)
{
    int t = blockIdx.x * blockDim.x + threadIdx.x;   // 65536 threads
    int n = t & 255;
    int j = t >> 8;
    float a = 0.f;
    for (int o = 0; o < HID; ++o)
        a += W2m[(size_t)j * HID + o] * W1u[(size_t)(128 + o) * HID + n];
    g_w1c[n * K1U + 128 + j] = f2bf(a);
    if (t < HID) {
        float c = 0.f;
        for (int o = 0; o < HID; ++o)
            c += b2m[o] * W1u[(size_t)(128 + o) * HID + t];
        g_bc[t] = c;
    }
}

__global__ __launch_bounds__(256) void dst_hist(const int* __restrict__ eidx)
{
    int e = blockIdx.x * blockDim.x + threadIdx.x;
    if (e < BE) {
        int dst = eidx[2 * e + 1];
        int b   = e / E_EDGES;
        atomicAdd(&g_hist[b * N_NODES + dst], 1);
    }
}

// ---------- hierarchical scan ----------

__global__ __launch_bounds__(1024) void scan_partial(
    int* __restrict__ offs, int* __restrict__ bsum)
{
    __shared__ int buf[1024];
    int tid = threadIdx.x;
    int i   = blockIdx.x * 1024 + tid;
    int v   = (i < BN) ? g_hist[i] : 0;
    buf[tid] = v;
    __syncthreads();
    #pragma unroll
    for (int d = 1; d < 1024; d <<= 1) {
        int t = (tid >= d) ? buf[tid - d] : 0;
        __syncthreads();
        buf[tid] += t;
        __syncthreads();
    }
    int incl = buf[tid];
    if (i < BN) offs[i] = incl - v;
    if (tid == 1023) bsum[blockIdx.x] = incl;
}

// scan_add with inline 20-element bsum prefix
__global__ __launch_bounds__(1024) void scan_add(
    int* __restrict__ offs, const int* __restrict__ bsum)
{
    __shared__ int sbase;
    int tid = threadIdx.x;
    if (tid < 64) {
        int v = (tid < blockIdx.x && tid < SCAN_BLOCKS) ? bsum[tid] : 0;
        #pragma unroll
        for (int d = 32; d > 0; d >>= 1) v += __shfl_down(v, d);
        if (tid == 0) sbase = v;
    }
    __syncthreads();
    int i = blockIdx.x * 1024 + tid;
    if (i < BN) offs[i] += sbase;
}

__global__ __launch_bounds__(256) void dst_scatter(
    const int* __restrict__ eidx, int* __restrict__ offs, int* __restrict__ perm)
{
    int e = blockIdx.x * blockDim.x + threadIdx.x;
    if (e < BE) {
        int dst  = eidx[2 * e + 1];
        int b    = e / E_EDGES;
        int pos  = atomicAdd(&offs[b * N_NODES + dst], 1);
        perm[pos] = e;
    }
}

// ---------- P GEMM: g_P[n][0:512) = nodef_bf @ [W1m[0:128] | W1m[128:256]] ----------
__global__ __launch_bounds__(512, 2) void pgemm(const unsigned short* __restrict__ w1t)
{
    const int tid  = threadIdx.x;
    const int wave = tid >> 6;
    const int lane = tid & 63;
    const int quad = lane >> 4;
    const int r16  = lane & 15;
    const int n0   = blockIdx.x * TM;

    const int jb   = (wave & 3) * 64;              // col base within 256
    const int koff = (wave < 4) ? 0 : 128;         // W1m k-row offset
    const int cb   = (wave < 4) ? 0 : 256;         // output col-base add

    f32x4 acc[4][4];
    #pragma unroll
    for (int mt = 0; mt < 4; ++mt)
        #pragma unroll
        for (int nt = 0; nt < 4; ++nt)
            acc[mt][nt] = (f32x4){0.f, 0.f, 0.f, 0.f};

    for (int ks = 0; ks < ND / 32; ++ks) {
        bf16x8 wf[4], nf[4];
        #pragma unroll
        for (int nt = 0; nt < 4; ++nt)
            wf[nt] = *(const bf16x8*)&w1t[(size_t)(jb + nt * 16 + r16) * K1
                                          + koff + ks * 32 + quad * 8];
        #pragma unroll
        for (int mt = 0; mt < 4; ++mt) {
            int row = n0 + mt * 16 + r16; if (row >= BN) row = BN - 1;
            nf[mt] = *(const bf16x8*)&g_nodef_bf[(size_t)row * ND + ks * 32 + quad * 8];
        }
        #pragma unroll
        for (int mt = 0; mt < 4; ++mt)
            #pragma unroll
            for (int nt = 0; nt < 4; ++nt)
                acc[mt][nt] = __builtin_amdgcn_mfma_f32_16x16x32_bf16(
                    wf[nt], nf[mt], acc[mt][nt], 0, 0, 0);
    }

    #pragma unroll
    for (int nt = 0; nt < 4; ++nt) {
        int j0 = cb + jb + nt * 16 + quad * 4;
        #pragma unroll
        for (int mt = 0; mt < 4; ++mt) {
            int m = n0 + mt * 16 + r16;
            if (m < BN) {
                float4 v = {acc[mt][nt][0], acc[mt][nt][1],
                            acc[mt][nt][2], acc[mt][nt][3]};
                *(float4*)&g_P[(size_t)m * 512 + j0] = v;
            }
        }
    }
}

// ---------- edge MLP (GEMM2 lifted out via linearity; h aggregated, not messages) ----------
// Per block (64 edges): stage edgef -> sE; GEMM1 (K=64, 8 MFMAs);
// gather P[src]+P[dst]+b1, gelu -> sH; run-reduce h into agg (atomics).
// LDS 41,984 B (+768 idx) -> 3 blocks/CU.
#define EK_SE   0
#define EK_SH   8192
#define EK_SMEM (8192 + TME * LDH * 2)   // 41,984

__global__ __launch_bounds__(512, 6) void edge_mlp_mfma(
    const int*            __restrict__ eidx,
    const float*          __restrict__ edgef,
    const int*            __restrict__ perm,
    const unsigned short* __restrict__ w1t,       // [256][320] bf16 n-major
    const float*          __restrict__ b1m,
    float* __restrict__ agg)                      // aggH: [BN][256] fp32
{
    __shared__ __align__(16) char smem[EK_SMEM];
    unsigned short* sE = (unsigned short*)(smem + EK_SE);
    unsigned short* sH = (unsigned short*)(smem + EK_SH);
    __shared__ int s_src[TME];
    __shared__ int s_dst[TME];
    __shared__ int s_eid[TME];

    const int tid  = threadIdx.x;
    const int wave = tid >> 6;
    const int lane = tid & 63;
    const int quad = lane >> 4;
    const int r16  = lane & 15;
    const int be0  = blockIdx.x * TME;

    if (tid < TME) {
        int eid = perm[be0 + tid];
        int b   = eid / E_EDGES;
        int2 se = ((const int2*)eidx)[eid];
        s_eid[tid] = eid;
        s_src[tid] = b * N_NODES + se.x;
        s_dst[tid] = b * N_NODES + se.y;
    }

    // GEMM1 weight A-frags (k-rows 256..319 of W1m): issue early, overlap staging.
    const unsigned short* wB1 = w1t + (size_t)(wave * 32) * K1 + 256;
    bf16x8 wf00 = *(const bf16x8*)&wB1[(size_t)r16        * K1 + quad * 8];
    bf16x8 wf01 = *(const bf16x8*)&wB1[(size_t)r16        * K1 + 32 + quad * 8];
    bf16x8 wf10 = *(const bf16x8*)&wB1[(size_t)(16 + r16) * K1 + quad * 8];
    bf16x8 wf11 = *(const bf16x8*)&wB1[(size_t)(16 + r16) * K1 + 32 + quad * 8];

    __syncthreads();   // s_eid visible

    // stage edge features fp32 -> bf16 panels: 2 x [64 rows x 32 k]
    {
        int row = tid >> 3;
        int c0  = (tid & 7) * 8;        // 0..56
        const float* fp = edgef + (size_t)s_eid[row] * ED + c0;
        float4 v0 = *(const float4*)fp;
        float4 v1 = *(const float4*)(fp + 4);
        ushort4 o0, o1;
        o0.x = f2bf(v0.x); o0.y = f2bf(v0.y); o0.z = f2bf(v0.z); o0.w = f2bf(v0.w);
        o1.x = f2bf(v1.x); o1.y = f2bf(v1.y); o1.z = f2bf(v1.z); o1.w = f2bf(v1.w);
        int p2 = c0 >> 5, kk = c0 & 31;
        *(ushort4*)&sE[p2 * 2048 + row * 32 + kk]     = o0;
        *(ushort4*)&sE[p2 * 2048 + row * 32 + kk + 4] = o1;
    }
    __syncthreads();

    f32x4 acc[4][2];
    #pragma unroll
    for (int mt = 0; mt < 4; ++mt)
        #pragma unroll
        for (int nt = 0; nt < 2; ++nt)
            acc[mt][nt] = (f32x4){0.f, 0.f, 0.f, 0.f};

    // ---- GEMM1: K=64 on edge features (A=weights, B=edge rows) ----
    #pragma unroll
    for (int mt = 0; mt < 4; ++mt) {
        bf16x8 e0 = *(const bf16x8*)&sE[(mt * 16 + r16) * 32 + quad * 8];
        bf16x8 e1 = *(const bf16x8*)&sE[2048 + (mt * 16 + r16) * 32 + quad * 8];
        acc[mt][0] = __builtin_amdgcn_mfma_f32_16x16x32_bf16(wf00, e0, acc[mt][0], 0, 0, 0);
        acc[mt][1] = __builtin_amdgcn_mfma_f32_16x16x32_bf16(wf10, e0, acc[mt][1], 0, 0, 0);
        acc[mt][0] = __builtin_amdgcn_mfma_f32_16x16x32_bf16(wf01, e1, acc[mt][0], 0, 0, 0);
        acc[mt][1] = __builtin_amdgcn_mfma_f32_16x16x32_bf16(wf11, e1, acc[mt][1], 0, 0, 0);
    }

    // ---- gather-add epilogue: + P[src] + P[dst] + b1, gelu -> sH (all float4) ----
    {
        float4 bb[2];
        bb[0] = *(const float4*)&b1m[wave * 32 + quad * 4];
        bb[1] = *(const float4*)&b1m[wave * 32 + 16 + quad * 4];
        #pragma unroll
        for (int mt = 0; mt < 4; ++mt) {
            int m = mt * 16 + r16;
            const float* pS = &g_P[(size_t)s_src[m] * 512];
            const float* pD = &g_P[(size_t)s_dst[m] * 512 + 256];
            #pragma unroll
            for (int nt = 0; nt < 2; ++nt) {
                int n0 = wave * 32 + nt * 16 + quad * 4;
                float4 vs = *(const float4*)(pS + n0);
                float4 vd = *(const float4*)(pD + n0);
                ushort4 o;
                o.x = f2bf(gelu_tanh(acc[mt][nt][0] + vs.x + vd.x + bb[nt].x));
                o.y = f2bf(gelu_tanh(acc[mt][nt][1] + vs.y + vd.y + bb[nt].y));
                o.z = f2bf(gelu_tanh(acc[mt][nt][2] + vs.z + vd.z + bb[nt].z));
                o.w = f2bf(gelu_tanh(acc[mt][nt][3] + vs.w + vd.w + bb[nt].w));
                *(ushort4*)&sH[m * LDH + n0] = o;
            }
        }
    }
    __syncthreads();   // sH visible to all waves

    // ---- run-reduce h into agg (sorted dst -> compacted atomics) ----
    {
        const int cc = tid & 255;          // column
        const int r0 = (tid >> 8) * 32;    // row-half base
        int   cur  = s_dst[r0];
        float racc = 0.f;
        for (int mb = 0; mb < 32; mb += 8) {
            float v[8];
            #pragma unroll
            for (int j = 0; j < 8; ++j)
                v[j] = bf2f(sH[(r0 + mb + j) * LDH + cc]);
            #pragma unroll
            for (int j = 0; j < 8; ++j) {
                int d = s_dst[r0 + mb + j];
                if (d != cur) {
                    atomicAdd(&agg[(size_t)cur * HID + cc], racc);
                    cur = d; racc = v[j];
                } else {
                    racc += v[j];
                }
            }
        }
        atomicAdd(&agg[(size_t)cur * HID + cc], racc);
    }
}

// ---------- node MLP: u_pre = nodef@W1u_a + aggH@Wc + hist*bc + b1u; out = gelu(u_pre)@W2u + b2u ----------
__global__ __launch_bounds__(256, 4) void node_mlp_mfma(
    const float* __restrict__ agg,
    const float* __restrict__ b1u,
    const float* __restrict__ b2u,
    float* __restrict__ out)
{
    __shared__ __align__(16) unsigned short sH[TM * LDH];

    const int tid  = threadIdx.x;
    const int wave = tid >> 6;
    const int lane = tid & 63;
    const int quad = lane >> 4;
    const int r16  = lane & 15;
    const int n0   = blockIdx.x * TM;

    f32x4 acc[4][4];
    #pragma unroll
    for (int mt = 0; mt < 4; ++mt)
        #pragma unroll
        for (int nt = 0; nt < 4; ++nt)
            acc[mt][nt] = (f32x4){0.f, 0.f, 0.f, 0.f};

    // ---- L1 part A: k in [0,128) from g_nodef_bf ----
    for (int ks = 0; ks < 4; ++ks) {
        bf16x8 wf[4], nf[4];
        #pragma unroll
        for (int nt = 0; nt < 4; ++nt)
            wf[nt] = *(const bf16x8*)&g_w1c[(size_t)(wave * 64 + nt * 16 + r16) * K1U
                                            + ks * 32 + quad * 8];
        #pragma unroll
        for (int mt = 0; mt < 4; ++mt) {
            int row = n0 + mt * 16 + r16; if (row >= BN) row = BN - 1;
            nf[mt] = *(const bf16x8*)&g_nodef_bf[(size_t)row * ND + ks * 32 + quad * 8];
        }
        #pragma unroll
        for (int mt = 0; mt < 4; ++mt)
            #pragma unroll
            for (int nt = 0; nt < 4; ++nt)
                acc[mt][nt] = __builtin_amdgcn_mfma_f32_16x16x32_bf16(
                    wf[nt], nf[mt], acc[mt][nt], 0, 0, 0);
    }
    // ---- L1 part B: k in [128,384) = aggH @ Wc (fp32 -> bf16 in regs) ----
    for (int ks = 0; ks < 8; ++ks) {
        bf16x8 wf[4], nf[4];
        #pragma unroll
        for (int nt = 0; nt < 4; ++nt)
            wf[nt] = *(const bf16x8*)&g_w1c[(size_t)(wave * 64 + nt * 16 + r16) * K1U
                                            + (4 + ks) * 32 + quad * 8];
        #pragma unroll
        for (int mt = 0; mt < 4; ++mt) {
            int row = n0 + mt * 16 + r16; if (row >= BN) row = BN - 1;
            const float* fp = &agg[(size_t)row * HID + ks * 32 + quad * 8];
            float4 v0 = *(const float4*)fp;
            float4 v1 = *(const float4*)(fp + 4);
            union { bf16x8 v; ushort4 u[2]; } cv;
            cv.u[0] = (ushort4){f2bf(v0.x), f2bf(v0.y), f2bf(v0.z), f2bf(v0.w)};
            cv.u[1] = (ushort4){f2bf(v1.x), f2bf(v1.y), f2bf(v1.z), f2bf(v1.w)};
            nf[mt] = cv.v;
        }
        #pragma unroll
        for (int mt = 0; mt < 4; ++mt)
            #pragma unroll
            for (int nt = 0; nt < 4; ++nt)
                acc[mt][nt] = __builtin_amdgcn_mfma_f32_16x16x32_bf16(
                    wf[nt], nf[mt], acc[mt][nt], 0, 0, 0);
    }

    // ---- L1 epilogue -> sH (ushort4 stores), bias = b1u + hist*bc ----
    #pragma unroll
    for (int nt = 0; nt < 4; ++nt) {
        int nn0 = wave * 64 + nt * 16 + quad * 4;
        float4 bb = *(const float4*)&b1u[nn0];
        float4 bc = *(const float4*)&g_bc[nn0];
        #pragma unroll
        for (int mt = 0; mt < 4; ++mt) {
            int row = n0 + mt * 16 + r16; if (row >= BN) row = BN - 1;
            float hv = (float)g_hist[row];
            int m = mt * 16 + r16;
            ushort4 o;
            o.x = f2bf(gelu_tanh(acc[mt][nt][0] + bb.x + hv * bc.x));
            o.y = f2bf(gelu_tanh(acc[mt][nt][1] + bb.y + hv * bc.y));
            o.z = f2bf(gelu_tanh(acc[mt][nt][2] + bb.z + hv * bc.z));
            o.w = f2bf(gelu_tanh(acc[mt][nt][3] + bb.w + hv * bc.w));
            *(ushort4*)&sH[m * LDH + nn0] = o;
        }
    }
    __syncthreads();

    f32x4 acc2[4][2];
    #pragma unroll
    for (int mt = 0; mt < 4; ++mt)
        #pragma unroll
        for (int nt = 0; nt < 2; ++nt)
            acc2[mt][nt] = (f32x4){0.f, 0.f, 0.f, 0.f};

    for (int ks = 0; ks < K2 / 32; ++ks) {
        bf16x8 wf2[2], hf[4];
        #pragma unroll
        for (int nt = 0; nt < 2; ++nt)
            wf2[nt] = *(const bf16x8*)&g_w2ut[(size_t)(wave * 32 + nt * 16 + r16) * K2
                                              + ks * 32 + quad * 8];
        #pragma unroll
        for (int mt = 0; mt < 4; ++mt)
            hf[mt] = *(const bf16x8*)&sH[(mt * 16 + r16) * LDH + ks * 32 + quad * 8];
        #pragma unroll
        for (int mt = 0; mt < 4; ++mt)
            #pragma unroll
            for (int nt = 0; nt < 2; ++nt)
                acc2[mt][nt] = __builtin_amdgcn_mfma_f32_16x16x32_bf16(
                    wf2[nt], hf[mt], acc2[mt][nt], 0, 0, 0);
    }

    // ---- L2 epilogue -> out (float4 stores) ----
    #pragma unroll
    for (int nt = 0; nt < 2; ++nt) {
        int j0 = wave * 32 + nt * 16 + quad * 4;
        float4 bb = *(const float4*)&b2u[j0];
        #pragma unroll
        for (int mt = 0; mt < 4; ++mt) {
            int row = n0 + mt * 16 + r16;
            if (row < BN) {
                float4 v = {acc2[mt][nt][0] + bb.x, acc2[mt][nt][1] + bb.y,
                            acc2[mt][nt][2] + bb.z, acc2[mt][nt][3] + bb.w};
                *(float4*)&out[(size_t)row * NOUT + j0] = v;
            }
        }
    }
}

// ---------- launch ----------
// ws: aggH [0 .. 20,480,000). d_out stash (read only before node_mlp_mfma runs):
//   w1t  [5,120,000 .. 5,283,840)
//   offs [5,494,912 .. 5,574,912)
//   perm [5,574,912 .. 6,854,912)
//   bsum [6,854,912 .. 6,855,040)
// hist/Wc/bc/P/nodef_bf in __device__ statics.

extern "C" void kernel_launch(void* const* d_in, const int* in_sizes, int n_in,
                              void* d_out, int out_size, void* d_ws, size_t ws_size,
                              hipStream_t stream) {
    const float* nodef = (const float*)d_in[0];
    const int*   eidx  = (const int*)  d_in[1];
    const float* edgef = (const float*)d_in[2];
    const float* W1m   = (const float*)d_in[3];
    const float* b1m   = (const float*)d_in[4];
    const float* W2m   = (const float*)d_in[5];
    const float* b2m   = (const float*)d_in[6];
    const float* W1u   = (const float*)d_in[7];
    const float* b1u   = (const float*)d_in[8];
    const float* W2u   = (const float*)d_in[9];
    const float* b2u   = (const float*)d_in[10];
    float* out = (float*)d_out;

    char* wsb = (char*)d_ws;
    float* agg = (float*)wsb;
    const size_t AGG_B = (size_t)BN * HID * sizeof(float);

    char* ob = (char*)d_out;
    unsigned short* w1t  = (unsigned short*)(ob + 5120000);
    int* offs            = (int*)(ob + 5494912);
    int* perm            = (int*)(ob + 5574912);
    int* bsum            = (int*)(ob + 6854912);

    hipMemsetAsync(agg, 0, AGG_B, stream);

    {
        int n4 = BN * ND / 4;
        f32_to_bf16_vec<<<(n4 + 255) / 256, 256, 0, stream>>>(nodef, n4);
    }
    prep_weights<<<(K1 * HID + 255) / 256, 256, 0, stream>>>(W1m, w1t, W1u, W2u);
    prep_wc<<<(HID * HID) / 256, 256, 0, stream>>>(W2m, W1u, b2m);

    pgemm<<<(BN + TM - 1) / TM, 512, 0, stream>>>(w1t);

    dst_hist<<<(BE + 255) / 256, 256, 0, stream>>>(eidx);
    scan_partial<<<SCAN_BLOCKS, 1024, 0, stream>>>(offs, bsum);
    scan_add<<<SCAN_BLOCKS, 1024, 0, stream>>>(offs, bsum);
    dst_scatter<<<(BE + 255) / 256, 256, 0, stream>>>(eidx, offs, perm);

    edge_mlp_mfma<<<BE / TME, 512, 0, stream>>>(
        eidx, edgef, perm, w1t, b1m, agg);

    node_mlp_mfma<<<(BN + TM - 1) / TM, 256, 0, stream>>>(agg, b1u, b2u, out);
}